// Round 9
// baseline (519.794 us; speedup 1.0000x reference)
//
#include <hip/hip_runtime.h>

#define NODES 16000
#define EDGES 256000
#define EMB   300
#define KP1   320      // padded EMB (mult of 32)
#define NP1   640      // padded 2*EMB (mult of 64)
#define NP2B  384      // padded rows for w2bT (3 x 128 tiles)
#define NGRAPH 64
#define LAYERS 5
#define INV_N (1.0f / 16000.0f)

typedef unsigned short u16;
typedef unsigned int u32;
typedef __bf16 bf16_t;
typedef bf16_t bf16x8 __attribute__((ext_vector_type(8)));
typedef float f32x4 __attribute__((ext_vector_type(4)));

__device__ inline u16 f2bf(float f) {
    bf16_t b = (bf16_t)f;
    return __builtin_bit_cast(u16, b);
}
__device__ inline float bf_lo(u32 u) { return __builtin_bit_cast(float, u << 16); }
__device__ inline float bf_hi(u32 u) { return __builtin_bit_cast(float, u & 0xFFFF0000u); }
__device__ inline u32 bf_pack(float lo, float hi) {
    return ((u32)f2bf(hi) << 16) | (u32)f2bf(lo);
}

__device__ inline float softplus_f(float x) {
    return fmaxf(x, 0.f) + log1pf(expf(-fabsf(x)));
}

// async global->LDS, 16B per lane; LDS dest is wave-uniform base + lane*16
__device__ inline void gload_lds16(const u16* g, u16* l) {
    __builtin_amdgcn_global_load_lds(
        (const __attribute__((address_space(1))) void*)g,
        (__attribute__((address_space(3))) void*)l, 16, 0, 0);
}

// BN affine from raw moments: y = x*s + t
__device__ inline void bn_coef_v(float ss, float qq, float gg, float bb,
                                 float& s, float& t) {
    float mean = ss * INV_N;
    float var = qq * INV_N - mean * mean;
    float rstd = rsqrtf(var + 1e-5f);
    s = rstd * gg;
    t = bb - mean * s;
}

// ---------------- CSR build (real edges only; self-loops analytic) -------------
__global__ void k_count(const int* __restrict__ ei, int* __restrict__ cnt) {
    int e = blockIdx.x * 256 + threadIdx.x;
    if (e >= EDGES) return;
    atomicAdd(&cnt[ei[EDGES + e]], 1);
}

// 1024 threads, 16 nodes/thread; wave shuffle-scan + LDS wave-prefix, 1 barrier.
__global__ __launch_bounds__(1024) void k_scan(const int* __restrict__ cnt,
                                               int* __restrict__ row_off,
                                               int* __restrict__ cursor) {
    __shared__ int wsum[16];
    int t = threadIdx.x;
    int lane = t & 63, w = t >> 6;
    int base = t * 16;
    int pre[16];
    int run = 0;
#pragma unroll
    for (int i = 0; i < 16; ++i) {
        int idx = base + i;
        int v = (idx < NODES) ? cnt[idx] : 0;
        pre[i] = run;
        run += v;
    }
    int inc = run;
#pragma unroll
    for (int off = 1; off < 64; off <<= 1) {
        int n = __shfl_up(inc, off);
        if (lane >= off) inc += n;
    }
    if (lane == 63) wsum[w] = inc;
    __syncthreads();
    int wpre = 0;
    for (int i = 0; i < w; ++i) wpre += wsum[i];
    int excl = wpre + inc - run;
#pragma unroll
    for (int i = 0; i < 16; ++i) {
        int idx = base + i;
        if (idx < NODES) {
            int st = excl + pre[i];
            row_off[idx] = st;
            cursor[idx] = st;
        }
    }
    if (t == 1023) row_off[NODES] = wpre + inc;
}

// fill CSR + per-node 18-class histogram (layer-invariant)
__global__ void k_fill(const int* __restrict__ ei, const int* __restrict__ ea,
                       int* __restrict__ cursor, int* __restrict__ packed,
                       int* __restrict__ cnt18) {
    int e = blockIdx.x * 256 + threadIdx.x;
    if (e >= EDGES) return;
    int src = ei[e];
    int dst = ei[EDGES + e];
    int c = ea[e * 2] * 3 + ea[e * 2 + 1];
    int pos = atomicAdd(&cursor[dst], 1);
    packed[pos] = src | (c << 20);
    atomicAdd(&cnt18[dst * 18 + c], 1);
}

// ---------------- fused setup: embed | comb | convw1 | convw2 | goff ----------
#define SEG0 1200000   // embed: NODES*EMB/4
#define SEG1 6750      // comb: 5*18*75
#define SEG2 256000    // convw1: 5*640*80
#define SEG3 307200    // convw2: 5*384*160
#define SETUP_TOT (SEG0 + SEG1 + SEG2 + SEG3 + NGRAPH + 1)

__global__ __launch_bounds__(256) void k_setup(
    const int* __restrict__ x, const float* __restrict__ e1x,
    const float* __restrict__ e2x, const float* __restrict__ ce1,
    const float* __restrict__ ce2, const float* __restrict__ w1,
    const float* __restrict__ w2, const int* __restrict__ batch,
    u16* __restrict__ h, u16* __restrict__ comb,
    u16* __restrict__ w1bT, u16* __restrict__ w2bT, int* __restrict__ goff) {
    int id = blockIdx.x * 256 + threadIdx.x;
    if (id < SEG0) {
        int base = id * 4;
        int row = base / EMB;
        int f = base - row * EMB;
        int x1 = x[2 * row], x2 = x[2 * row + 1];
        float4 a = *(const float4*)(e1x + x1 * EMB + f);
        float4 b = *(const float4*)(e2x + x2 * EMB + f);
        u32* o = (u32*)h + id * 2;
        o[0] = bf_pack(a.x + b.x, a.y + b.y);
        o[1] = bf_pack(a.z + b.z, a.w + b.w);
        return;
    }
    id -= SEG0;
    if (id < SEG1) {
        int l = id / 1350, r = id - l * 1350;
        int c = r / 75, f = (r - c * 75) * 4;
        int a = c / 3, bb = c - a * 3;
        float4 va = *(const float4*)(ce1 + (l * 6 + a) * EMB + f);
        float4 vb = *(const float4*)(ce2 + (l * 3 + bb) * EMB + f);
        u32* o = (u32*)comb + ((l * 18 + c) * EMB + f) / 2;
        o[0] = bf_pack(va.x + vb.x, va.y + vb.y);
        o[1] = bf_pack(va.z + vb.z, va.w + vb.w);
        return;
    }
    id -= SEG1;
    if (id < SEG2) {  // w1bT[l][n][k] = w1[l][k][n], pad to [640][320]
        int l = id / (NP1 * 80), r = id - l * (NP1 * 80);
        int n = r / 80, k4 = (r - n * 80) * 4;
        float v[4];
#pragma unroll
        for (int j = 0; j < 4; ++j) {
            int k = k4 + j;
            v[j] = (n < 600 && k < EMB) ? w1[(l * EMB + k) * 600 + n] : 0.f;
        }
        u32* o = (u32*)w1bT + ((size_t)(l * NP1 + n) * KP1 + k4) / 2;
        o[0] = bf_pack(v[0], v[1]);
        o[1] = bf_pack(v[2], v[3]);
        return;
    }
    id -= SEG2;
    if (id < SEG3) {  // w2bT[l][n][k] = w2[l][k][n], pad to [384][640]
        int l = id / (NP2B * 160), r = id - l * (NP2B * 160);
        int n = r / 160, k4 = (r - n * 160) * 4;
        float v[4];
#pragma unroll
        for (int j = 0; j < 4; ++j) {
            int k = k4 + j;
            v[j] = (n < EMB && k < 600) ? w2[(l * 600 + k) * EMB + n] : 0.f;
        }
        u32* o = (u32*)w2bT + ((size_t)(l * NP2B + n) * NP1 + k4) / 2;
        o[0] = bf_pack(v[0], v[1]);
        o[1] = bf_pack(v[2], v[3]);
        return;
    }
    id -= SEG3;
    if (id <= NGRAPH) {
        int lo = 0, hi = NODES;
        while (lo < hi) { int mid = (lo + hi) >> 1; if (batch[mid] < id) lo = mid + 1; else hi = mid; }
        goff[id] = lo;
    }
}

// ---------------- BN+relu hoisted: h' = relu(h*s + t), bf16->bf16, 4 elems/thr -
__global__ __launch_bounds__(256) void k_bnrelu(
    const u16* __restrict__ hin, u16* __restrict__ hout,
    const float* __restrict__ ssum, const float* __restrict__ ssq,
    const float* __restrict__ g, const float* __restrict__ b) {
    int id = blockIdx.x * 256 + threadIdx.x;
    if (id >= NODES * EMB / 4) return;
    int base = id * 4;
    int row = base / EMB;
    int f = base - row * EMB;  // f % 4 == 0 since 4 | 300
    float4 S = *(const float4*)(ssum + f);
    float4 Q = *(const float4*)(ssq + f);
    float4 G = *(const float4*)(g + f);
    float4 B = *(const float4*)(b + f);
    const u32* in = (const u32*)hin + id * 2;
    u32 x0 = in[0], x1 = in[1];
    float sc0, tc0, sc1, tc1, sc2, tc2, sc3, tc3;
    bn_coef_v(S.x, Q.x, G.x, B.x, sc0, tc0);
    bn_coef_v(S.y, Q.y, G.y, B.y, sc1, tc1);
    bn_coef_v(S.z, Q.z, G.z, B.z, sc2, tc2);
    bn_coef_v(S.w, Q.w, G.w, B.w, sc3, tc3);
    float v0 = fmaxf(bf_lo(x0) * sc0 + tc0, 0.f);
    float v1 = fmaxf(bf_hi(x0) * sc1 + tc1, 0.f);
    float v2 = fmaxf(bf_lo(x1) * sc2 + tc2, 0.f);
    float v3 = fmaxf(bf_hi(x1) * sc3 + tc3, 0.f);
    u32* o = (u32*)hout + id * 2;
    o[0] = bf_pack(v0, v1);
    o[1] = bf_pack(v2, v3);
}

// ---------------- aggregation: h-gather loop + 18-class comb epilogue ----------
// Lane owns u32 feature-pairs {2l, 2l+1} (dwordx2) and {128+l} (l<22).
// comb term = sum_c cnt18[node][c] * comb[c]  (+1 on class 15 for the self-loop).
#define AGG_E(Q)                                                \
    {                                                           \
        const u32* hr = hu + (size_t)((Q) & 0xFFFFF) * 150;     \
        uint2 u01 = *(const uint2*)(hr + 2 * lane);             \
        u32 u2 = 0;                                             \
        if (has2) u2 = hr[128 + lane];                          \
        a0l += bf_lo(u01.x); a0h += bf_hi(u01.x);               \
        a1l += bf_lo(u01.y); a1h += bf_hi(u01.y);               \
        a2l += bf_lo(u2);    a2h += bf_hi(u2);                  \
    }

__global__ __launch_bounds__(256) void k_aggregate(
    const u16* __restrict__ h, const int* __restrict__ row_off,
    const int* __restrict__ packed, const u16* __restrict__ comb,
    const int* __restrict__ cnt18, u16* __restrict__ aggB) {
    int node = blockIdx.x * 4 + (threadIdx.x >> 6);
    int lane = threadIdx.x & 63;
    int s = row_off[node], e = row_off[node + 1];
    bool has2 = lane < 22;  // features 256..299 = 22 u32 pairs
    const u32* hu = (const u32*)h;
    const u32* cu = (const u32*)comb;
    float a0l = 0, a0h = 0, a1l = 0, a1h = 0, a2l = 0, a2h = 0;
    // self-loop h[node]
    {
        const u32* hr = hu + (size_t)node * 150;
        uint2 u01 = *(const uint2*)(hr + 2 * lane);
        u32 u2 = 0;
        if (has2) u2 = hr[128 + lane];
        a0l = bf_lo(u01.x); a0h = bf_hi(u01.x);
        a1l = bf_lo(u01.y); a1h = bf_hi(u01.y);
        a2l = bf_lo(u2);    a2h = bf_hi(u2);
    }
    int p = s;
    for (; p + 3 < e; p += 4) {
        int q0 = __builtin_amdgcn_readfirstlane(packed[p]);
        int q1 = __builtin_amdgcn_readfirstlane(packed[p + 1]);
        int q2 = __builtin_amdgcn_readfirstlane(packed[p + 2]);
        int q3 = __builtin_amdgcn_readfirstlane(packed[p + 3]);
        AGG_E(q0); AGG_E(q1); AGG_E(q2); AGG_E(q3);
    }
    for (; p < e; ++p) {
        int q = __builtin_amdgcn_readfirstlane(packed[p]);
        AGG_E(q);
    }
    // comb epilogue: counts * comb rows (self-loop adds 1 to class 15)
    const int* cb = cnt18 + node * 18;
#pragma unroll
    for (int c = 0; c < 18; ++c) {
        int cv = cb[c] + (c == 15 ? 1 : 0);
        if (cv) {
            float fc = (float)cv;
            const u32* cr = cu + c * 150;
            uint2 v01 = *(const uint2*)(cr + 2 * lane);
            u32 v2 = 0;
            if (has2) v2 = cr[128 + lane];
            a0l += fc * bf_lo(v01.x); a0h += fc * bf_hi(v01.x);
            a1l += fc * bf_lo(v01.y); a1h += fc * bf_hi(v01.y);
            a2l += fc * bf_lo(v2);    a2h += fc * bf_hi(v2);
        }
    }
    u32* o = (u32*)(aggB + (size_t)node * KP1);
    uint2 w01;
    w01.x = bf_pack(a0l, a0h);
    w01.y = bf_pack(a1l, a1h);
    *(uint2*)(o + 2 * lane) = w01;
    if (lane < 32) o[128 + lane] = has2 ? bf_pack(a2l, a2h) : 0u;  // pads 300..319
}

// ---------------- bf16 MFMA GEMM, 128x128 tile, global_load_lds staging --------
// m97 structure: linear LDS [128][32] u16, 2 barriers/K-step, 16 MFMA/step.
// grid (N/128, M/128): N-tile on x (fastest) so consecutive blocks share A panel.
// MODE 0: +bias, relu, bf16 store (ldc stride)
// MODE 1: +bias, bf16 store (EMB stride, col<300) + fused column stats
template <int MODE>
__global__ __launch_bounds__(256) void k_gemm(
    const u16* __restrict__ A, const u16* __restrict__ Bt,
    const float* __restrict__ bias, int nbias,
    u16* __restrict__ Cv, int ldc, int K,
    float* __restrict__ ssum, float* __restrict__ ssq) {
    __shared__ __align__(16) u16 Al[128 * 32];
    __shared__ __align__(16) u16 Bl[128 * 32];
    __shared__ float rs[2][128];
    __shared__ float rq[2][128];
    int t = threadIdx.x;
    int n0 = blockIdx.x * 128, m0 = blockIdx.y * 128;
    int lane = t & 63, w = t >> 6;
    int wr = w >> 1, wc = w & 1;
    int lr = lane >> 2, lc = lane & 3;
    const u16* gA0 = A + (size_t)(m0 + w * 32 + lr) * K + lc * 8;
    const u16* gA1 = gA0 + (size_t)16 * K;
    const u16* gB0 = Bt + (size_t)(n0 + w * 32 + lr) * K + lc * 8;
    const u16* gB1 = gB0 + (size_t)16 * K;
    u16* lA0 = &Al[(w * 32) * 32];
    u16* lA1 = &Al[(w * 32 + 16) * 32];
    u16* lB0 = &Bl[(w * 32) * 32];
    u16* lB1 = &Bl[(w * 32 + 16) * 32];
    f32x4 acc[4][4];
#pragma unroll
    for (int i = 0; i < 4; i++)
#pragma unroll
        for (int j = 0; j < 4; j++) acc[i][j] = (f32x4){0.f, 0.f, 0.f, 0.f};
    int fr = lane & 15;
    int k0 = (lane >> 4) * 8;
    int abase = (wr * 64 + fr) * 32 + k0;
    int bbase = (wc * 64 + fr) * 32 + k0;
    for (int kt = 0; kt < K; kt += 32) {
        if (kt) __syncthreads();
        gload_lds16(gA0 + kt, lA0);
        gload_lds16(gA1 + kt, lA1);
        gload_lds16(gB0 + kt, lB0);
        gload_lds16(gB1 + kt, lB1);
        __syncthreads();
        bf16x8 af[4], bfv[4];
#pragma unroll
        for (int f = 0; f < 4; ++f) {
            af[f]  = *reinterpret_cast<const bf16x8*>(&Al[abase + f * 16 * 32]);
            bfv[f] = *reinterpret_cast<const bf16x8*>(&Bl[bbase + f * 16 * 32]);
        }
#pragma unroll
        for (int fm = 0; fm < 4; ++fm)
#pragma unroll
            for (int fn = 0; fn < 4; ++fn)
                acc[fm][fn] = __builtin_amdgcn_mfma_f32_16x16x32_bf16(
                    af[fm], bfv[fn], acc[fm][fn], 0, 0, 0);
    }
    int rg = lane >> 4;
    if (MODE == 0) {
#pragma unroll
        for (int fn = 0; fn < 4; ++fn) {
            int col = n0 + wc * 64 + fn * 16 + fr;
            float bv = (col < nbias) ? bias[col] : 0.f;
#pragma unroll
            for (int fm = 0; fm < 4; ++fm) {
                int rb = m0 + wr * 64 + fm * 16 + rg * 4;
#pragma unroll
                for (int j = 0; j < 4; ++j) {
                    float v = fmaxf(acc[fm][fn][j] + bv, 0.f);
                    Cv[(size_t)(rb + j) * ldc + col] = f2bf(v);
                }
            }
        }
    } else {
#pragma unroll
        for (int fn = 0; fn < 4; ++fn) {
            int col = n0 + wc * 64 + fn * 16 + fr;
            float bv = (col < nbias) ? bias[col] : 0.f;
            float cs = 0.f, cq = 0.f;
#pragma unroll
            for (int fm = 0; fm < 4; ++fm) {
                int rb = m0 + wr * 64 + fm * 16 + rg * 4;
#pragma unroll
                for (int j = 0; j < 4; ++j) {
                    float v = acc[fm][fn][j] + bv;
                    if (col < EMB) Cv[(size_t)(rb + j) * EMB + col] = f2bf(v);
                    cs += v;
                    cq += v * v;
                }
            }
            cs += __shfl_xor(cs, 16); cs += __shfl_xor(cs, 32);
            cq += __shfl_xor(cq, 16); cq += __shfl_xor(cq, 32);
            if (rg == 0) {
                rs[wr][wc * 64 + fn * 16 + fr] = cs;
                rq[wr][wc * 64 + fn * 16 + fr] = cq;
            }
        }
        __syncthreads();
        if (t < 128) {
            int col = n0 + t;
            if (col < EMB) {
                atomicAdd(&ssum[col], rs[0][t] + rs[1][t]);
                atomicAdd(&ssq[col], rq[0][t] + rq[1][t]);
            }
        }
    }
}

// ---------------- tail: pool (fused final BN), head GEMMs ----------------------
__global__ __launch_bounds__(256) void k_pool(const u16* __restrict__ h,
                                              const int* __restrict__ goff,
                                              const float* __restrict__ ssum,
                                              const float* __restrict__ ssq,
                                              const float* __restrict__ bng,
                                              const float* __restrict__ bnb,
                                              float* __restrict__ hg) {
    __shared__ float red[4][64];
    int g = blockIdx.x;
    int col = blockIdx.y * 64 + (threadIdx.x & 63);
    int w = threadIdx.x >> 6;
    int s = goff[g], e = goff[g + 1];
    float a = 0.f;
    bool ok = col < EMB;
    if (ok) {
        for (int r = s + w; r < e; r += 4)
            a += __builtin_bit_cast(float, (u32)h[(size_t)r * EMB + col] << 16);
    }
    red[w][threadIdx.x & 63] = a;
    __syncthreads();
    if (w == 0 && ok) {
        float sc, tc;
        bn_coef_v(ssum[col], ssq[col], bng[col], bnb[col], sc, tc);
        float v = red[0][threadIdx.x] + red[1][threadIdx.x] +
                  red[2][threadIdx.x] + red[3][threadIdx.x];
        float inv = (e > s) ? 1.0f / (float)(e - s) : 0.f;
        hg[(size_t)g * EMB + col] = (v * inv) * sc + tc;
    }
}

template <int ACT>  // 0: none, 1: softplus
__global__ __launch_bounds__(256) void k_small_mm(
    const float* __restrict__ A, const float* __restrict__ W,
    const float* __restrict__ bias, float* __restrict__ C, int N, int K) {
    __shared__ float red[4][64];
    int row = blockIdx.x;
    int lane = threadIdx.x & 63;
    int col = blockIdx.y * 64 + lane;
    int w = threadIdx.x >> 6;
    const float* a = A + (size_t)row * K;
    float acc = 0.f;
#pragma unroll 4
    for (int k = w; k < K; k += 4) acc += a[k] * W[(size_t)k * N + col];
    red[w][lane] = acc;
    __syncthreads();
    if (w == 0) {
        float v = red[0][lane] + red[1][lane] + red[2][lane] + red[3][lane] + bias[col];
        if (ACT) v = softplus_f(v);
        C[(size_t)row * N + col] = v;
    }
}

__global__ __launch_bounds__(256) void k_pred(const float* __restrict__ P,
                                              const float* __restrict__ hw3,
                                              const float* __restrict__ hb3,
                                              float* __restrict__ out) {
    __shared__ float red[2][4];
    int g = blockIdx.x;
    int t = threadIdx.x;
    float q = P[(size_t)g * 256 + t];
    float r0 = q * hw3[t * 2 + 0];
    float r1 = q * hw3[t * 2 + 1];
#pragma unroll
    for (int off = 32; off > 0; off >>= 1) {
        r0 += __shfl_down(r0, off);
        r1 += __shfl_down(r1, off);
    }
    if ((t & 63) == 0) { red[0][t >> 6] = r0; red[1][t >> 6] = r1; }
    __syncthreads();
    if (t == 0) {
        out[(size_t)NGRAPH * 512 + g * 2 + 0] = red[0][0] + red[0][1] + red[0][2] + red[0][3] + hb3[0];
        out[(size_t)NGRAPH * 512 + g * 2 + 1] = red[1][0] + red[1][1] + red[1][2] + red[1][3] + hb3[1];
    }
}

// ---------------- launch ----------------
extern "C" void kernel_launch(void* const* d_in, const int* in_sizes, int n_in,
                              void* d_out, int out_size, void* d_ws, size_t ws_size,
                              hipStream_t stream) {
    const int* x      = (const int*)d_in[0];
    const int* ei     = (const int*)d_in[1];
    const int* ea     = (const int*)d_in[2];
    const int* batch  = (const int*)d_in[3];
    const float* x_emb1 = (const float*)d_in[4];
    const float* x_emb2 = (const float*)d_in[5];
    const float* e1_emb = (const float*)d_in[6];
    const float* e2_emb = (const float*)d_in[7];
    const float* w1   = (const float*)d_in[8];
    const float* b1   = (const float*)d_in[9];
    const float* w2   = (const float*)d_in[10];
    const float* b2   = (const float*)d_in[11];
    const float* bn_g = (const float*)d_in[12];
    const float* bn_b = (const float*)d_in[13];
    const float* feat_w = (const float*)d_in[14];
    const float* feat_b = (const float*)d_in[15];
    const float* hw1  = (const float*)d_in[16];
    const float* hb1  = (const float*)d_in[17];
    const float* hw2  = (const float*)d_in[18];
    const float* hb2  = (const float*)d_in[19];
    const float* hw3  = (const float*)d_in[20];
    const float* hb3  = (const float*)d_in[21];
    float* out = (float*)d_out;

    char* p = (char*)d_ws;
    auto alloc = [&](size_t bytes) -> char* {
        char* r = p;
        p += ((bytes + 255) / 256) * 256;
        return r;
    };
    u16* h_a     = (u16*)alloc((size_t)NODES * EMB * 2);   // current h (pre-BN)
    u16* h_b     = (u16*)alloc((size_t)NODES * EMB * 2);   // post-BN h'
    u16* aggB    = (u16*)alloc((size_t)NODES * KP1 * 2);
    u16* T       = (u16*)alloc((size_t)NODES * NP1 * 2);
    u16* w1bT    = (u16*)alloc((size_t)LAYERS * NP1 * KP1 * 2);
    u16* w2bT    = (u16*)alloc((size_t)LAYERS * NP2B * NP1 * 2);
    u16* comb    = (u16*)alloc((size_t)LAYERS * 18 * EMB * 2);
    int* row_off = (int*)alloc((NODES + 1) * 4);
    int* packed  = (int*)alloc((size_t)EDGES * 4);
    int* goff    = (int*)alloc((NGRAPH + 1) * 4);
    float* hg    = (float*)alloc((size_t)NGRAPH * EMB * 4);
    float* pb1   = (float*)alloc((size_t)NGRAPH * 256 * 4);
    float* pb2   = (float*)alloc((size_t)NGRAPH * 256 * 4);
    // cursor + stats + cnt18 contiguous -> single memset
    int* cursor   = (int*)alloc(NODES * 4);                    // 64000 B
    float* stats5 = (float*)alloc((size_t)LAYERS * 640 * 4);   // 12800 B
    int* cnt18    = (int*)alloc((size_t)NODES * 18 * 4);       // 1152000 B
    if ((size_t)(p - (char*)d_ws) > ws_size) return;  // workspace too small

    hipMemsetAsync(cursor, 0, NODES * 4 + LAYERS * 640 * 4 + (size_t)NODES * 18 * 4,
                   stream);

    // CSR build (real edges only; self-loops analytic in k_aggregate)
    k_count<<<(EDGES + 255) / 256, 256, 0, stream>>>(ei, cursor);
    k_scan<<<1, 1024, 0, stream>>>(cursor, row_off, cursor);
    k_fill<<<(EDGES + 255) / 256, 256, 0, stream>>>(ei, ea, cursor, packed, cnt18);

    // fused setup: embed -> h_a, comb, w1bT, w2bT, goff
    k_setup<<<(SETUP_TOT + 255) / 256, 256, 0, stream>>>(
        x, x_emb1, x_emb2, e1_emb, e2_emb, w1, w2, batch,
        h_a, comb, w1bT, w2bT, goff);

    for (int l = 0; l < LAYERS; ++l) {
        const u16* h_src;
        if (l == 0) {
            h_src = h_a;
        } else {
            float* st = stats5 + (size_t)(l - 1) * 640;
            k_bnrelu<<<(NODES * EMB / 4 + 255) / 256, 256, 0, stream>>>(
                h_a, h_b, st, st + 320, bn_g + (l - 1) * EMB, bn_b + (l - 1) * EMB);
            h_src = h_b;
        }
        k_aggregate<<<NODES / 4, 256, 0, stream>>>(
            h_src, row_off, packed, comb + (size_t)l * 18 * EMB, cnt18, aggB);
        k_gemm<0><<<dim3(NP1 / 128, NODES / 128), 256, 0, stream>>>(
            aggB, w1bT + (size_t)l * NP1 * KP1, b1 + l * 600, 600, T, NP1, KP1,
            nullptr, nullptr);
        float* st = stats5 + (size_t)l * 640;
        k_gemm<1><<<dim3(NP2B / 128, NODES / 128), 256, 0, stream>>>(
            T, w2bT + (size_t)l * NP2B * NP1, b2 + l * EMB, EMB, h_a, 0, NP1,
            st, st + 320);
    }

    // h_a holds layer-4 pre-BN output; pool applies BN affine post-mean
    float* st4 = stats5 + (size_t)4 * 640;
    k_pool<<<dim3(NGRAPH, 5), 256, 0, stream>>>(h_a, goff, st4, st4 + 320,
                                                bn_g + 4 * EMB, bn_b + 4 * EMB, hg);
    k_small_mm<0><<<dim3(NGRAPH, 8), 256, 0, stream>>>(hg, feat_w, feat_b, out, 512, EMB);
    k_small_mm<1><<<dim3(NGRAPH, 4), 256, 0, stream>>>(out, hw1, hb1, pb1, 256, 512);
    k_small_mm<1><<<dim3(NGRAPH, 4), 256, 0, stream>>>(pb1, hw2, hb2, pb2, 256, 256);
    k_pred<<<NGRAPH, 256, 0, stream>>>(pb2, hw3, hb3, out);
}

// Round 10
// 465.362 us; speedup vs baseline: 1.1170x; 1.1170x over previous
//
#include <hip/hip_runtime.h>

#define NODES 16000
#define EDGES 256000
#define EMB   300
#define KP1   320      // padded EMB (mult of 32)
#define NP1   640      // padded 2*EMB (mult of 64)
#define NP2B  384      // padded rows for w2bT (3 x 128 tiles)
#define NGRAPH 64
#define LAYERS 5
#define INV_N (1.0f / 16000.0f)

typedef unsigned short u16;
typedef unsigned int u32;
typedef __bf16 bf16_t;
typedef bf16_t bf16x8 __attribute__((ext_vector_type(8)));
typedef float f32x4 __attribute__((ext_vector_type(4)));

__device__ inline u16 f2bf(float f) {
    bf16_t b = (bf16_t)f;
    return __builtin_bit_cast(u16, b);
}
__device__ inline float bf_lo(u32 u) { return __builtin_bit_cast(float, u << 16); }
__device__ inline float bf_hi(u32 u) { return __builtin_bit_cast(float, u & 0xFFFF0000u); }
__device__ inline u32 bf_pack(float lo, float hi) {
    return ((u32)f2bf(hi) << 16) | (u32)f2bf(lo);
}

__device__ inline float softplus_f(float x) {
    return fmaxf(x, 0.f) + log1pf(expf(-fabsf(x)));
}

// async global->LDS, 16B per lane; LDS dest is wave-uniform base + lane*16
__device__ inline void gload_lds16(const u16* g, u16* l) {
    __builtin_amdgcn_global_load_lds(
        (const __attribute__((address_space(1))) void*)g,
        (__attribute__((address_space(3))) void*)l, 16, 0, 0);
}

// BN affine from raw moments: y = x*s + t
__device__ inline void bn_coef_v(float ss, float qq, float gg, float bb,
                                 float& s, float& t) {
    float mean = ss * INV_N;
    float var = qq * INV_N - mean * mean;
    float rstd = rsqrtf(var + 1e-5f);
    s = rstd * gg;
    t = bb - mean * s;
}

// ---------------- CSR build (real edges only; self-loops analytic) -------------
__global__ void k_count(const int* __restrict__ ei, int* __restrict__ cnt) {
    int e = blockIdx.x * 256 + threadIdx.x;
    if (e >= EDGES) return;
    atomicAdd(&cnt[ei[EDGES + e]], 1);
}

// 1024 threads, 16 nodes/thread; wave shuffle-scan + LDS wave-prefix, 1 barrier.
__global__ __launch_bounds__(1024) void k_scan(const int* __restrict__ cnt,
                                               int* __restrict__ row_off,
                                               int* __restrict__ cursor) {
    __shared__ int wsum[16];
    int t = threadIdx.x;
    int lane = t & 63, w = t >> 6;
    int base = t * 16;
    int pre[16];
    int run = 0;
#pragma unroll
    for (int i = 0; i < 16; ++i) {
        int idx = base + i;
        int v = (idx < NODES) ? cnt[idx] : 0;
        pre[i] = run;
        run += v;
    }
    int inc = run;
#pragma unroll
    for (int off = 1; off < 64; off <<= 1) {
        int n = __shfl_up(inc, off);
        if (lane >= off) inc += n;
    }
    if (lane == 63) wsum[w] = inc;
    __syncthreads();
    int wpre = 0;
    for (int i = 0; i < w; ++i) wpre += wsum[i];
    int excl = wpre + inc - run;
#pragma unroll
    for (int i = 0; i < 16; ++i) {
        int idx = base + i;
        if (idx < NODES) {
            int st = excl + pre[i];
            row_off[idx] = st;
            cursor[idx] = st;
        }
    }
    if (t == 1023) row_off[NODES] = wpre + inc;
}

__global__ void k_fill(const int* __restrict__ ei, const int* __restrict__ ea,
                       int* __restrict__ cursor, int* __restrict__ packed) {
    int e = blockIdx.x * 256 + threadIdx.x;
    if (e >= EDGES) return;
    int src = ei[e];
    int dst = ei[EDGES + e];
    int c = ea[e * 2] * 3 + ea[e * 2 + 1];
    int pos = atomicAdd(&cursor[dst], 1);
    packed[pos] = src | (c << 20);
}

// ---------------- fused setup: embed | comb | convw1 | convw2 | goff ----------
#define SEG0 1200000   // embed: NODES*EMB/4
#define SEG1 6750      // comb: 5*18*75
#define SEG2 256000    // convw1: 5*640*80
#define SEG3 307200    // convw2: 5*384*160
#define SETUP_TOT (SEG0 + SEG1 + SEG2 + SEG3 + NGRAPH + 1)

__global__ __launch_bounds__(256) void k_setup(
    const int* __restrict__ x, const float* __restrict__ e1x,
    const float* __restrict__ e2x, const float* __restrict__ ce1,
    const float* __restrict__ ce2, const float* __restrict__ w1,
    const float* __restrict__ w2, const int* __restrict__ batch,
    u16* __restrict__ h, u16* __restrict__ comb,
    u16* __restrict__ w1bT, u16* __restrict__ w2bT, int* __restrict__ goff) {
    int id = blockIdx.x * 256 + threadIdx.x;
    if (id < SEG0) {
        int base = id * 4;
        int row = base / EMB;
        int f = base - row * EMB;
        int x1 = x[2 * row], x2 = x[2 * row + 1];
        float4 a = *(const float4*)(e1x + x1 * EMB + f);
        float4 b = *(const float4*)(e2x + x2 * EMB + f);
        u32* o = (u32*)h + id * 2;
        o[0] = bf_pack(a.x + b.x, a.y + b.y);
        o[1] = bf_pack(a.z + b.z, a.w + b.w);
        return;
    }
    id -= SEG0;
    if (id < SEG1) {
        int l = id / 1350, r = id - l * 1350;
        int c = r / 75, f = (r - c * 75) * 4;
        int a = c / 3, bb = c - a * 3;
        float4 va = *(const float4*)(ce1 + (l * 6 + a) * EMB + f);
        float4 vb = *(const float4*)(ce2 + (l * 3 + bb) * EMB + f);
        u32* o = (u32*)comb + ((l * 18 + c) * EMB + f) / 2;
        o[0] = bf_pack(va.x + vb.x, va.y + vb.y);
        o[1] = bf_pack(va.z + vb.z, va.w + vb.w);
        return;
    }
    id -= SEG1;
    if (id < SEG2) {  // w1bT[l][n][k] = w1[l][k][n], pad to [640][320]
        int l = id / (NP1 * 80), r = id - l * (NP1 * 80);
        int n = r / 80, k4 = (r - n * 80) * 4;
        float v[4];
#pragma unroll
        for (int j = 0; j < 4; ++j) {
            int k = k4 + j;
            v[j] = (n < 600 && k < EMB) ? w1[(l * EMB + k) * 600 + n] : 0.f;
        }
        u32* o = (u32*)w1bT + ((size_t)(l * NP1 + n) * KP1 + k4) / 2;
        o[0] = bf_pack(v[0], v[1]);
        o[1] = bf_pack(v[2], v[3]);
        return;
    }
    id -= SEG2;
    if (id < SEG3) {  // w2bT[l][n][k] = w2[l][k][n], pad to [384][640]
        int l = id / (NP2B * 160), r = id - l * (NP2B * 160);
        int n = r / 160, k4 = (r - n * 160) * 4;
        float v[4];
#pragma unroll
        for (int j = 0; j < 4; ++j) {
            int k = k4 + j;
            v[j] = (n < EMB && k < 600) ? w2[(l * 600 + k) * EMB + n] : 0.f;
        }
        u32* o = (u32*)w2bT + ((size_t)(l * NP2B + n) * NP1 + k4) / 2;
        o[0] = bf_pack(v[0], v[1]);
        o[1] = bf_pack(v[2], v[3]);
        return;
    }
    id -= SEG3;
    if (id <= NGRAPH) {
        int lo = 0, hi = NODES;
        while (lo < hi) { int mid = (lo + hi) >> 1; if (batch[mid] < id) lo = mid + 1; else hi = mid; }
        goff[id] = lo;
    }
}

// ---------------- BN+relu hoisted: h' = relu(h*s + t), bf16->bf16, 4 elems/thr -
__global__ __launch_bounds__(256) void k_bnrelu(
    const u16* __restrict__ hin, u16* __restrict__ hout,
    const float* __restrict__ ssum, const float* __restrict__ ssq,
    const float* __restrict__ g, const float* __restrict__ b) {
    int id = blockIdx.x * 256 + threadIdx.x;
    if (id >= NODES * EMB / 4) return;
    int base = id * 4;
    int row = base / EMB;
    int f = base - row * EMB;  // f % 4 == 0 since 4 | 300
    float4 S = *(const float4*)(ssum + f);
    float4 Q = *(const float4*)(ssq + f);
    float4 G = *(const float4*)(g + f);
    float4 B = *(const float4*)(b + f);
    const u32* in = (const u32*)hin + id * 2;
    u32 x0 = in[0], x1 = in[1];
    float sc0, tc0, sc1, tc1, sc2, tc2, sc3, tc3;
    bn_coef_v(S.x, Q.x, G.x, B.x, sc0, tc0);
    bn_coef_v(S.y, Q.y, G.y, B.y, sc1, tc1);
    bn_coef_v(S.z, Q.z, G.z, B.z, sc2, tc2);
    bn_coef_v(S.w, Q.w, G.w, B.w, sc3, tc3);
    float v0 = fmaxf(bf_lo(x0) * sc0 + tc0, 0.f);
    float v1 = fmaxf(bf_hi(x0) * sc1 + tc1, 0.f);
    float v2 = fmaxf(bf_lo(x1) * sc2 + tc2, 0.f);
    float v3 = fmaxf(bf_hi(x1) * sc3 + tc3, 0.f);
    u32* o = (u32*)hout + id * 2;
    o[0] = bf_pack(v0, v1);
    o[1] = bf_pack(v2, v3);
}

// ---------------- aggregation: one wave per node, scalar edge bases ------------
// Per edge: packed word readfirstlane'd to SGPR -> h/comb row bases are scalar;
// loads are s[base] + lane*4 (+imm). Self-loop (h[node] + comb[15]) in the init.
#define AGG_E(Q)                                                \
    {                                                           \
        const u32* hr = hu + (size_t)((Q) & 0xFFFFF) * 150;     \
        const u32* cr = cu + ((Q) >> 20) * 150;                 \
        u32 u0 = hr[lane], u1 = hr[64 + lane];                  \
        u32 v0 = cr[lane], v1 = cr[64 + lane];                  \
        u32 u2 = 0, v2 = 0;                                     \
        if (has2) { u2 = hr[128 + lane]; v2 = cr[128 + lane]; } \
        a0l += bf_lo(u0) + bf_lo(v0);                           \
        a0h += bf_hi(u0) + bf_hi(v0);                           \
        a1l += bf_lo(u1) + bf_lo(v1);                           \
        a1h += bf_hi(u1) + bf_hi(v1);                           \
        a2l += bf_lo(u2) + bf_lo(v2);                           \
        a2h += bf_hi(u2) + bf_hi(v2);                           \
    }

__global__ __launch_bounds__(256) void k_aggregate(
    const u16* __restrict__ h, const int* __restrict__ row_off,
    const int* __restrict__ packed, const u16* __restrict__ comb,
    u16* __restrict__ aggB) {
    int node = blockIdx.x * 4 + (threadIdx.x >> 6);
    int lane = threadIdx.x & 63;
    int s = row_off[node], e = row_off[node + 1];
    bool has2 = lane < 22;  // features 256..299 = 22 uint pairs
    const u32* hu = (const u32*)h;
    const u32* cu = (const u32*)comb;
    float a0l = 0, a0h = 0, a1l = 0, a1h = 0, a2l = 0, a2h = 0;
    // self-loop: h[node] + comb[15]  (attr (5,0) -> 5*3+0)
    {
        const u32* hr = hu + (size_t)node * 150;
        const u32* cr = cu + 15 * 150;
        u32 u0 = hr[lane], u1 = hr[64 + lane];
        u32 v0 = cr[lane], v1 = cr[64 + lane];
        u32 u2 = 0, v2 = 0;
        if (has2) { u2 = hr[128 + lane]; v2 = cr[128 + lane]; }
        a0l = bf_lo(u0) + bf_lo(v0);
        a0h = bf_hi(u0) + bf_hi(v0);
        a1l = bf_lo(u1) + bf_lo(v1);
        a1h = bf_hi(u1) + bf_hi(v1);
        a2l = bf_lo(u2) + bf_lo(v2);
        a2h = bf_hi(u2) + bf_hi(v2);
    }
    int p = s;
    for (; p + 3 < e; p += 4) {
        int q0 = __builtin_amdgcn_readfirstlane(packed[p]);
        int q1 = __builtin_amdgcn_readfirstlane(packed[p + 1]);
        int q2 = __builtin_amdgcn_readfirstlane(packed[p + 2]);
        int q3 = __builtin_amdgcn_readfirstlane(packed[p + 3]);
        AGG_E(q0); AGG_E(q1); AGG_E(q2); AGG_E(q3);
    }
    for (; p < e; ++p) {
        int q = __builtin_amdgcn_readfirstlane(packed[p]);
        AGG_E(q);
    }
    u32* o = (u32*)(aggB + (size_t)node * KP1);
    o[lane] = bf_pack(a0l, a0h);
    o[64 + lane] = bf_pack(a1l, a1h);
    if (lane < 32) o[128 + lane] = has2 ? bf_pack(a2l, a2h) : 0u;  // pads 300..319
}

// ---------------- bf16 MFMA GEMM, 128x128 tile, double-buffered prefetch -------
// T3 "minimum 2-phase": stage tile t+1 BEFORE compute of tile t; one
// __syncthreads per K-step (its implicit vmcnt(0)+lgkmcnt(0) drain gives the
// needed semantics). LDS 2x(8+8) KB linear [128][32] u16.
// MODE 0: +bias, relu, bf16 store (ldc stride)
// MODE 1: +bias, bf16 store (EMB stride, col<300) + fused column stats
template <int MODE>
__global__ __launch_bounds__(256) void k_gemm(
    const u16* __restrict__ A, const u16* __restrict__ Bt,
    const float* __restrict__ bias, int nbias,
    u16* __restrict__ Cv, int ldc, int K,
    float* __restrict__ ssum, float* __restrict__ ssq) {
    __shared__ __align__(16) u16 Al[2][128 * 32];
    __shared__ __align__(16) u16 Bl[2][128 * 32];
    __shared__ float rs[2][128];
    __shared__ float rq[2][128];
    int t = threadIdx.x;
    int n0 = blockIdx.x * 128, m0 = blockIdx.y * 128;
    int lane = t & 63, w = t >> 6;
    int wr = w >> 1, wc = w & 1;
    int lr = lane >> 2, lc = lane & 3;
    const u16* gA0 = A + (size_t)(m0 + w * 32 + lr) * K + lc * 8;
    const u16* gA1 = gA0 + (size_t)16 * K;
    const u16* gB0 = Bt + (size_t)(n0 + w * 32 + lr) * K + lc * 8;
    const u16* gB1 = gB0 + (size_t)16 * K;
    int lds0 = (w * 32) * 32;
    int lds1 = (w * 32 + 16) * 32;
    f32x4 acc[4][4];
#pragma unroll
    for (int i = 0; i < 4; i++)
#pragma unroll
        for (int j = 0; j < 4; j++) acc[i][j] = (f32x4){0.f, 0.f, 0.f, 0.f};
    int fr = lane & 15;
    int k0 = (lane >> 4) * 8;
    int abase = (wr * 64 + fr) * 32 + k0;
    int bbase = (wc * 64 + fr) * 32 + k0;
    int nsteps = K >> 5;
    // prologue: stage tile 0 into buffer 0
    gload_lds16(gA0, &Al[0][lds0]);
    gload_lds16(gA1, &Al[0][lds1]);
    gload_lds16(gB0, &Bl[0][lds0]);
    gload_lds16(gB1, &Bl[0][lds1]);
    __syncthreads();  // vmcnt(0) drain -> tile 0 visible
    int cur = 0;
    for (int s = 0; s < nsteps; ++s) {
        if (s + 1 < nsteps) {  // issue next tile's staging before compute
            int kt = (s + 1) << 5;
            gload_lds16(gA0 + kt, &Al[cur ^ 1][lds0]);
            gload_lds16(gA1 + kt, &Al[cur ^ 1][lds1]);
            gload_lds16(gB0 + kt, &Bl[cur ^ 1][lds0]);
            gload_lds16(gB1 + kt, &Bl[cur ^ 1][lds1]);
        }
        bf16x8 af[4], bfv[4];
#pragma unroll
        for (int f = 0; f < 4; ++f) {
            af[f]  = *reinterpret_cast<const bf16x8*>(&Al[cur][abase + f * 16 * 32]);
            bfv[f] = *reinterpret_cast<const bf16x8*>(&Bl[cur][bbase + f * 16 * 32]);
        }
#pragma unroll
        for (int fm = 0; fm < 4; ++fm)
#pragma unroll
            for (int fn = 0; fn < 4; ++fn)
                acc[fm][fn] = __builtin_amdgcn_mfma_f32_16x16x32_bf16(
                    af[fm], bfv[fn], acc[fm][fn], 0, 0, 0);
        if (s + 1 < nsteps) {
            __syncthreads();  // drains vmcnt(0)+lgkmcnt(0): next tile ready,
            cur ^= 1;         // and all waves done reading buf[cur]
        }
    }
    int rg = lane >> 4;
    if (MODE == 0) {
#pragma unroll
        for (int fn = 0; fn < 4; ++fn) {
            int col = n0 + wc * 64 + fn * 16 + fr;
            float bv = (col < nbias) ? bias[col] : 0.f;
#pragma unroll
            for (int fm = 0; fm < 4; ++fm) {
                int rb = m0 + wr * 64 + fm * 16 + rg * 4;
#pragma unroll
                for (int j = 0; j < 4; ++j) {
                    float v = fmaxf(acc[fm][fn][j] + bv, 0.f);
                    Cv[(size_t)(rb + j) * ldc + col] = f2bf(v);
                }
            }
        }
    } else {
#pragma unroll
        for (int fn = 0; fn < 4; ++fn) {
            int col = n0 + wc * 64 + fn * 16 + fr;
            float bv = (col < nbias) ? bias[col] : 0.f;
            float cs = 0.f, cq = 0.f;
#pragma unroll
            for (int fm = 0; fm < 4; ++fm) {
                int rb = m0 + wr * 64 + fm * 16 + rg * 4;
#pragma unroll
                for (int j = 0; j < 4; ++j) {
                    float v = acc[fm][fn][j] + bv;
                    if (col < EMB) Cv[(size_t)(rb + j) * EMB + col] = f2bf(v);
                    cs += v;
                    cq += v * v;
                }
            }
            cs += __shfl_xor(cs, 16); cs += __shfl_xor(cs, 32);
            cq += __shfl_xor(cq, 16); cq += __shfl_xor(cq, 32);
            if (rg == 0) {
                rs[wr][wc * 64 + fn * 16 + fr] = cs;
                rq[wr][wc * 64 + fn * 16 + fr] = cq;
            }
        }
        __syncthreads();
        if (t < 128) {
            int col = n0 + t;
            if (col < EMB) {
                atomicAdd(&ssum[col], rs[0][t] + rs[1][t]);
                atomicAdd(&ssq[col], rq[0][t] + rq[1][t]);
            }
        }
    }
}

// ---------------- tail: pool (fused final BN), head GEMMs ----------------------
__global__ __launch_bounds__(256) void k_pool(const u16* __restrict__ h,
                                              const int* __restrict__ goff,
                                              const float* __restrict__ ssum,
                                              const float* __restrict__ ssq,
                                              const float* __restrict__ bng,
                                              const float* __restrict__ bnb,
                                              float* __restrict__ hg) {
    __shared__ float red[4][64];
    int g = blockIdx.x;
    int col = blockIdx.y * 64 + (threadIdx.x & 63);
    int w = threadIdx.x >> 6;
    int s = goff[g], e = goff[g + 1];
    float a = 0.f;
    bool ok = col < EMB;
    if (ok) {
        for (int r = s + w; r < e; r += 4)
            a += __builtin_bit_cast(float, (u32)h[(size_t)r * EMB + col] << 16);
    }
    red[w][threadIdx.x & 63] = a;
    __syncthreads();
    if (w == 0 && ok) {
        float sc, tc;
        bn_coef_v(ssum[col], ssq[col], bng[col], bnb[col], sc, tc);
        float v = red[0][threadIdx.x] + red[1][threadIdx.x] +
                  red[2][threadIdx.x] + red[3][threadIdx.x];
        float inv = (e > s) ? 1.0f / (float)(e - s) : 0.f;
        hg[(size_t)g * EMB + col] = (v * inv) * sc + tc;
    }
}

template <int ACT>  // 0: none, 1: softplus
__global__ __launch_bounds__(256) void k_small_mm(
    const float* __restrict__ A, const float* __restrict__ W,
    const float* __restrict__ bias, float* __restrict__ C, int N, int K) {
    __shared__ float red[4][64];
    int row = blockIdx.x;
    int lane = threadIdx.x & 63;
    int col = blockIdx.y * 64 + lane;
    int w = threadIdx.x >> 6;
    const float* a = A + (size_t)row * K;
    float acc = 0.f;
#pragma unroll 4
    for (int k = w; k < K; k += 4) acc += a[k] * W[(size_t)k * N + col];
    red[w][lane] = acc;
    __syncthreads();
    if (w == 0) {
        float v = red[0][lane] + red[1][lane] + red[2][lane] + red[3][lane] + bias[col];
        if (ACT) v = softplus_f(v);
        C[(size_t)row * N + col] = v;
    }
}

__global__ __launch_bounds__(256) void k_pred(const float* __restrict__ P,
                                              const float* __restrict__ hw3,
                                              const float* __restrict__ hb3,
                                              float* __restrict__ out) {
    __shared__ float red[2][4];
    int g = blockIdx.x;
    int t = threadIdx.x;
    float q = P[(size_t)g * 256 + t];
    float r0 = q * hw3[t * 2 + 0];
    float r1 = q * hw3[t * 2 + 1];
#pragma unroll
    for (int off = 32; off > 0; off >>= 1) {
        r0 += __shfl_down(r0, off);
        r1 += __shfl_down(r1, off);
    }
    if ((t & 63) == 0) { red[0][t >> 6] = r0; red[1][t >> 6] = r1; }
    __syncthreads();
    if (t == 0) {
        out[(size_t)NGRAPH * 512 + g * 2 + 0] = red[0][0] + red[0][1] + red[0][2] + red[0][3] + hb3[0];
        out[(size_t)NGRAPH * 512 + g * 2 + 1] = red[1][0] + red[1][1] + red[1][2] + red[1][3] + hb3[1];
    }
}

// ---------------- launch ----------------
extern "C" void kernel_launch(void* const* d_in, const int* in_sizes, int n_in,
                              void* d_out, int out_size, void* d_ws, size_t ws_size,
                              hipStream_t stream) {
    const int* x      = (const int*)d_in[0];
    const int* ei     = (const int*)d_in[1];
    const int* ea     = (const int*)d_in[2];
    const int* batch  = (const int*)d_in[3];
    const float* x_emb1 = (const float*)d_in[4];
    const float* x_emb2 = (const float*)d_in[5];
    const float* e1_emb = (const float*)d_in[6];
    const float* e2_emb = (const float*)d_in[7];
    const float* w1   = (const float*)d_in[8];
    const float* b1   = (const float*)d_in[9];
    const float* w2   = (const float*)d_in[10];
    const float* b2   = (const float*)d_in[11];
    const float* bn_g = (const float*)d_in[12];
    const float* bn_b = (const float*)d_in[13];
    const float* feat_w = (const float*)d_in[14];
    const float* feat_b = (const float*)d_in[15];
    const float* hw1  = (const float*)d_in[16];
    const float* hb1  = (const float*)d_in[17];
    const float* hw2  = (const float*)d_in[18];
    const float* hb2  = (const float*)d_in[19];
    const float* hw3  = (const float*)d_in[20];
    const float* hb3  = (const float*)d_in[21];
    float* out = (float*)d_out;

    char* p = (char*)d_ws;
    auto alloc = [&](size_t bytes) -> char* {
        char* r = p;
        p += ((bytes + 255) / 256) * 256;
        return r;
    };
    u16* h_a     = (u16*)alloc((size_t)NODES * EMB * 2);   // current h (pre-BN)
    u16* h_b     = (u16*)alloc((size_t)NODES * EMB * 2);   // post-BN h'
    u16* aggB    = (u16*)alloc((size_t)NODES * KP1 * 2);
    u16* T       = (u16*)alloc((size_t)NODES * NP1 * 2);
    u16* w1bT    = (u16*)alloc((size_t)LAYERS * NP1 * KP1 * 2);
    u16* w2bT    = (u16*)alloc((size_t)LAYERS * NP2B * NP1 * 2);
    u16* comb    = (u16*)alloc((size_t)LAYERS * 18 * EMB * 2);
    int* row_off = (int*)alloc((NODES + 1) * 4);
    int* packed  = (int*)alloc((size_t)EDGES * 4);
    int* goff    = (int*)alloc((NGRAPH + 1) * 4);
    float* hg    = (float*)alloc((size_t)NGRAPH * EMB * 4);
    float* pb1   = (float*)alloc((size_t)NGRAPH * 256 * 4);
    float* pb2   = (float*)alloc((size_t)NGRAPH * 256 * 4);
    // cursor + per-layer stats contiguous -> single memset
    int* cursor  = (int*)alloc(NODES * 4);                 // 64000 B (256-mult)
    float* stats5 = (float*)alloc((size_t)LAYERS * 640 * 4);  // [l][ssum320|ssq320]
    if ((size_t)(p - (char*)d_ws) > ws_size) return;  // workspace too small

    hipMemsetAsync(cursor, 0, NODES * 4 + LAYERS * 640 * 4, stream);

    // CSR build (real edges only; self-loops analytic in k_aggregate)
    k_count<<<(EDGES + 255) / 256, 256, 0, stream>>>(ei, cursor);
    k_scan<<<1, 1024, 0, stream>>>(cursor, row_off, cursor);
    k_fill<<<(EDGES + 255) / 256, 256, 0, stream>>>(ei, ea, cursor, packed);

    // fused setup: embed -> h_a, comb, w1bT, w2bT, goff
    k_setup<<<(SETUP_TOT + 255) / 256, 256, 0, stream>>>(
        x, x_emb1, x_emb2, e1_emb, e2_emb, w1, w2, batch,
        h_a, comb, w1bT, w2bT, goff);

    for (int l = 0; l < LAYERS; ++l) {
        const u16* h_src;
        if (l == 0) {
            h_src = h_a;
        } else {
            float* st = stats5 + (size_t)(l - 1) * 640;
            k_bnrelu<<<(NODES * EMB / 4 + 255) / 256, 256, 0, stream>>>(
                h_a, h_b, st, st + 320, bn_g + (l - 1) * EMB, bn_b + (l - 1) * EMB);
            h_src = h_b;
        }
        k_aggregate<<<NODES / 4, 256, 0, stream>>>(
            h_src, row_off, packed, comb + (size_t)l * 18 * EMB, aggB);
        k_gemm<0><<<dim3(NP1 / 128, NODES / 128), 256, 0, stream>>>(
            aggB, w1bT + (size_t)l * NP1 * KP1, b1 + l * 600, 600, T, NP1, KP1,
            nullptr, nullptr);
        float* st = stats5 + (size_t)l * 640;
        k_gemm<1><<<dim3(NP2B / 128, NODES / 128), 256, 0, stream>>>(
            T, w2bT + (size_t)l * NP2B * NP1, b2 + l * EMB, EMB, h_a, 0, NP1,
            st, st + 320);
    }

    // h_a holds layer-4 pre-BN output; pool applies BN affine post-mean
    float* st4 = stats5 + (size_t)4 * 640;
    k_pool<<<dim3(NGRAPH, 5), 256, 0, stream>>>(h_a, goff, st4, st4 + 320,
                                                bn_g + 4 * EMB, bn_b + 4 * EMB, hg);
    k_small_mm<0><<<dim3(NGRAPH, 8), 256, 0, stream>>>(hg, feat_w, feat_b, out, 512, EMB);
    k_small_mm<1><<<dim3(NGRAPH, 4), 256, 0, stream>>>(out, hw1, hb1, pb1, 256, 512);
    k_small_mm<1><<<dim3(NGRAPH, 4), 256, 0, stream>>>(pb1, hw2, hb2, pb2, 256, 256);
    k_pred<<<NGRAPH, 256, 0, stream>>>(pb2, hw3, hb3, out);
}

// Round 11
// 439.299 us; speedup vs baseline: 1.1832x; 1.0593x over previous
//
#include <hip/hip_runtime.h>

#define NODES 16000
#define EDGES 256000
#define EMB   300
#define KP1   320      // padded EMB (mult of 32)
#define NP1   640      // padded 2*EMB (mult of 64)
#define NP2B  384      // padded rows for w2bT (3 x 128 tiles)
#define NGRAPH 64
#define LAYERS 5
#define INV_N (1.0f / 16000.0f)
#define NXCD  8

typedef unsigned short u16;
typedef unsigned int u32;
typedef __bf16 bf16_t;
typedef bf16_t bf16x8 __attribute__((ext_vector_type(8)));
typedef float f32x4 __attribute__((ext_vector_type(4)));

__device__ inline u16 f2bf(float f) {
    bf16_t b = (bf16_t)f;
    return __builtin_bit_cast(u16, b);
}
__device__ inline float bf_lo(u32 u) { return __builtin_bit_cast(float, u << 16); }
__device__ inline float bf_hi(u32 u) { return __builtin_bit_cast(float, u & 0xFFFF0000u); }
__device__ inline u32 bf_pack(float lo, float hi) {
    return ((u32)f2bf(hi) << 16) | (u32)f2bf(lo);
}

__device__ inline float softplus_f(float x) {
    return fmaxf(x, 0.f) + log1pf(expf(-fabsf(x)));
}

// async global->LDS, 16B per lane; LDS dest is wave-uniform base + lane*16
__device__ inline void gload_lds16(const u16* g, u16* l) {
    __builtin_amdgcn_global_load_lds(
        (const __attribute__((address_space(1))) void*)g,
        (__attribute__((address_space(3))) void*)l, 16, 0, 0);
}

// bijective XCD-chunked remap (m204): orig round-robins XCDs; result gives each
// XCD a contiguous chunk. Works for any nwg.
__device__ inline int xcd_chunk(int orig, int nwg) {
    int q = nwg >> 3, r = nwg & 7;
    int xcd = orig & 7, idx = orig >> 3;
    return (xcd < r ? xcd * (q + 1) : r * (q + 1) + (xcd - r) * q) + idx;
}

// BN affine from raw moments: y = x*s + t
__device__ inline void bn_coef_v(float ss, float qq, float gg, float bb,
                                 float& s, float& t) {
    float mean = ss * INV_N;
    float var = qq * INV_N - mean * mean;
    float rstd = rsqrtf(var + 1e-5f);
    s = rstd * gg;
    t = bb - mean * s;
}

// ---------------- CSR build (real edges only; self-loops analytic) -------------
__global__ void k_count(const int* __restrict__ ei, int* __restrict__ cnt) {
    int e = blockIdx.x * 256 + threadIdx.x;
    if (e >= EDGES) return;
    atomicAdd(&cnt[ei[EDGES + e]], 1);
}

// 1024 threads, 16 nodes/thread; wave shuffle-scan + LDS wave-prefix, 1 barrier.
__global__ __launch_bounds__(1024) void k_scan(const int* __restrict__ cnt,
                                               int* __restrict__ row_off,
                                               int* __restrict__ cursor) {
    __shared__ int wsum[16];
    int t = threadIdx.x;
    int lane = t & 63, w = t >> 6;
    int base = t * 16;
    int pre[16];
    int run = 0;
#pragma unroll
    for (int i = 0; i < 16; ++i) {
        int idx = base + i;
        int v = (idx < NODES) ? cnt[idx] : 0;
        pre[i] = run;
        run += v;
    }
    int inc = run;
#pragma unroll
    for (int off = 1; off < 64; off <<= 1) {
        int n = __shfl_up(inc, off);
        if (lane >= off) inc += n;
    }
    if (lane == 63) wsum[w] = inc;
    __syncthreads();
    int wpre = 0;
    for (int i = 0; i < w; ++i) wpre += wsum[i];
    int excl = wpre + inc - run;
#pragma unroll
    for (int i = 0; i < 16; ++i) {
        int idx = base + i;
        if (idx < NODES) {
            int st = excl + pre[i];
            row_off[idx] = st;
            cursor[idx] = st;
        }
    }
    if (t == 1023) row_off[NODES] = wpre + inc;
}

__global__ void k_fill(const int* __restrict__ ei, const int* __restrict__ ea,
                       int* __restrict__ cursor, int* __restrict__ packed) {
    int e = blockIdx.x * 256 + threadIdx.x;
    if (e >= EDGES) return;
    int src = ei[e];
    int dst = ei[EDGES + e];
    int c = ea[e * 2] * 3 + ea[e * 2 + 1];
    int pos = atomicAdd(&cursor[dst], 1);
    packed[pos] = src | (c << 20);
}

// ---------------- fused setup: embed | comb | convw1 | convw2 | goff ----------
#define SEG0 1200000   // embed: NODES*EMB/4
#define SEG1 6750      // comb: 5*18*75
#define SEG2 256000    // convw1: 5*640*80
#define SEG3 307200    // convw2: 5*384*160
#define SETUP_TOT (SEG0 + SEG1 + SEG2 + SEG3 + NGRAPH + 1)

__global__ __launch_bounds__(256) void k_setup(
    const int* __restrict__ x, const float* __restrict__ e1x,
    const float* __restrict__ e2x, const float* __restrict__ ce1,
    const float* __restrict__ ce2, const float* __restrict__ w1,
    const float* __restrict__ w2, const int* __restrict__ batch,
    u16* __restrict__ h, u16* __restrict__ comb,
    u16* __restrict__ w1bT, u16* __restrict__ w2bT, int* __restrict__ goff) {
    int id = blockIdx.x * 256 + threadIdx.x;
    if (id < SEG0) {
        int base = id * 4;
        int row = base / EMB;
        int f = base - row * EMB;
        int x1 = x[2 * row], x2 = x[2 * row + 1];
        float4 a = *(const float4*)(e1x + x1 * EMB + f);
        float4 b = *(const float4*)(e2x + x2 * EMB + f);
        u32* o = (u32*)h + id * 2;
        o[0] = bf_pack(a.x + b.x, a.y + b.y);
        o[1] = bf_pack(a.z + b.z, a.w + b.w);
        return;
    }
    id -= SEG0;
    if (id < SEG1) {
        int l = id / 1350, r = id - l * 1350;
        int c = r / 75, f = (r - c * 75) * 4;
        int a = c / 3, bb = c - a * 3;
        float4 va = *(const float4*)(ce1 + (l * 6 + a) * EMB + f);
        float4 vb = *(const float4*)(ce2 + (l * 3 + bb) * EMB + f);
        u32* o = (u32*)comb + ((l * 18 + c) * EMB + f) / 2;
        o[0] = bf_pack(va.x + vb.x, va.y + vb.y);
        o[1] = bf_pack(va.z + vb.z, va.w + vb.w);
        return;
    }
    id -= SEG1;
    if (id < SEG2) {  // w1bT[l][n][k] = w1[l][k][n], pad to [640][320]
        int l = id / (NP1 * 80), r = id - l * (NP1 * 80);
        int n = r / 80, k4 = (r - n * 80) * 4;
        float v[4];
#pragma unroll
        for (int j = 0; j < 4; ++j) {
            int k = k4 + j;
            v[j] = (n < 600 && k < EMB) ? w1[(l * EMB + k) * 600 + n] : 0.f;
        }
        u32* o = (u32*)w1bT + ((size_t)(l * NP1 + n) * KP1 + k4) / 2;
        o[0] = bf_pack(v[0], v[1]);
        o[1] = bf_pack(v[2], v[3]);
        return;
    }
    id -= SEG2;
    if (id < SEG3) {  // w2bT[l][n][k] = w2[l][k][n], pad to [384][640]
        int l = id / (NP2B * 160), r = id - l * (NP2B * 160);
        int n = r / 160, k4 = (r - n * 160) * 4;
        float v[4];
#pragma unroll
        for (int j = 0; j < 4; ++j) {
            int k = k4 + j;
            v[j] = (n < EMB && k < 600) ? w2[(l * 600 + k) * EMB + n] : 0.f;
        }
        u32* o = (u32*)w2bT + ((size_t)(l * NP2B + n) * NP1 + k4) / 2;
        o[0] = bf_pack(v[0], v[1]);
        o[1] = bf_pack(v[2], v[3]);
        return;
    }
    id -= SEG3;
    if (id <= NGRAPH) {
        int lo = 0, hi = NODES;
        while (lo < hi) { int mid = (lo + hi) >> 1; if (batch[mid] < id) lo = mid + 1; else hi = mid; }
        goff[id] = lo;
    }
}

// ---------------- BN+relu hoisted: h' = relu(h*s + t), bf16->bf16, 4 elems/thr -
__global__ __launch_bounds__(256) void k_bnrelu(
    const u16* __restrict__ hin, u16* __restrict__ hout,
    const float* __restrict__ ssum, const float* __restrict__ ssq,
    const float* __restrict__ g, const float* __restrict__ b) {
    int id = blockIdx.x * 256 + threadIdx.x;
    if (id >= NODES * EMB / 4) return;
    int base = id * 4;
    int row = base / EMB;
    int f = base - row * EMB;  // f % 4 == 0 since 4 | 300
    float4 S = *(const float4*)(ssum + f);
    float4 Q = *(const float4*)(ssq + f);
    float4 G = *(const float4*)(g + f);
    float4 B = *(const float4*)(b + f);
    const u32* in = (const u32*)hin + id * 2;
    u32 x0 = in[0], x1 = in[1];
    float sc0, tc0, sc1, tc1, sc2, tc2, sc3, tc3;
    bn_coef_v(S.x, Q.x, G.x, B.x, sc0, tc0);
    bn_coef_v(S.y, Q.y, G.y, B.y, sc1, tc1);
    bn_coef_v(S.z, Q.z, G.z, B.z, sc2, tc2);
    bn_coef_v(S.w, Q.w, G.w, B.w, sc3, tc3);
    float v0 = fmaxf(bf_lo(x0) * sc0 + tc0, 0.f);
    float v1 = fmaxf(bf_hi(x0) * sc1 + tc1, 0.f);
    float v2 = fmaxf(bf_lo(x1) * sc2 + tc2, 0.f);
    float v3 = fmaxf(bf_hi(x1) * sc3 + tc3, 0.f);
    u32* o = (u32*)hout + id * 2;
    o[0] = bf_pack(v0, v1);
    o[1] = bf_pack(v2, v3);
}

// ---------------- aggregation: one wave per node, scalar edge bases ------------
// XCD-chunked block swizzle: each XCD owns a contiguous ~2000-node range whose
// graph-local gathers (~1.2 MB of h) fit its 4 MiB L2.
#define AGG_E(Q)                                                \
    {                                                           \
        const u32* hr = hu + (size_t)((Q) & 0xFFFFF) * 150;     \
        const u32* cr = cu + ((Q) >> 20) * 150;                 \
        u32 u0 = hr[lane], u1 = hr[64 + lane];                  \
        u32 v0 = cr[lane], v1 = cr[64 + lane];                  \
        u32 u2 = 0, v2 = 0;                                     \
        if (has2) { u2 = hr[128 + lane]; v2 = cr[128 + lane]; } \
        a0l += bf_lo(u0) + bf_lo(v0);                           \
        a0h += bf_hi(u0) + bf_hi(v0);                           \
        a1l += bf_lo(u1) + bf_lo(v1);                           \
        a1h += bf_hi(u1) + bf_hi(v1);                           \
        a2l += bf_lo(u2) + bf_lo(v2);                           \
        a2h += bf_hi(u2) + bf_hi(v2);                           \
    }

__global__ __launch_bounds__(256) void k_aggregate(
    const u16* __restrict__ h, const int* __restrict__ row_off,
    const int* __restrict__ packed, const u16* __restrict__ comb,
    u16* __restrict__ aggB) {
    int blk = xcd_chunk(blockIdx.x, NODES / 4);  // 4000 % 8 == 0
    int node = blk * 4 + (threadIdx.x >> 6);
    int lane = threadIdx.x & 63;
    int s = row_off[node], e = row_off[node + 1];
    bool has2 = lane < 22;  // features 256..299 = 22 uint pairs
    const u32* hu = (const u32*)h;
    const u32* cu = (const u32*)comb;
    float a0l = 0, a0h = 0, a1l = 0, a1h = 0, a2l = 0, a2h = 0;
    // self-loop: h[node] + comb[15]  (attr (5,0) -> 5*3+0)
    {
        const u32* hr = hu + (size_t)node * 150;
        const u32* cr = cu + 15 * 150;
        u32 u0 = hr[lane], u1 = hr[64 + lane];
        u32 v0 = cr[lane], v1 = cr[64 + lane];
        u32 u2 = 0, v2 = 0;
        if (has2) { u2 = hr[128 + lane]; v2 = cr[128 + lane]; }
        a0l = bf_lo(u0) + bf_lo(v0);
        a0h = bf_hi(u0) + bf_hi(v0);
        a1l = bf_lo(u1) + bf_lo(v1);
        a1h = bf_hi(u1) + bf_hi(v1);
        a2l = bf_lo(u2) + bf_lo(v2);
        a2h = bf_hi(u2) + bf_hi(v2);
    }
    int p = s;
    for (; p + 3 < e; p += 4) {
        int q0 = __builtin_amdgcn_readfirstlane(packed[p]);
        int q1 = __builtin_amdgcn_readfirstlane(packed[p + 1]);
        int q2 = __builtin_amdgcn_readfirstlane(packed[p + 2]);
        int q3 = __builtin_amdgcn_readfirstlane(packed[p + 3]);
        AGG_E(q0); AGG_E(q1); AGG_E(q2); AGG_E(q3);
    }
    for (; p < e; ++p) {
        int q = __builtin_amdgcn_readfirstlane(packed[p]);
        AGG_E(q);
    }
    u32* o = (u32*)(aggB + (size_t)node * KP1);
    o[lane] = bf_pack(a0l, a0h);
    o[64 + lane] = bf_pack(a1l, a1h);
    if (lane < 32) o[128 + lane] = has2 ? bf_pack(a2l, a2h) : 0u;  // pads 300..319
}

// ---------------- bf16 MFMA GEMM, 128x128 tile, global_load_lds staging --------
// m97 structure: linear LDS [128][32] u16, 2 barriers/K-step, 16 MFMA/step.
// XCD-chunked remap of the flat tile id: all N-tiles of an M-panel land on one
// XCD and reuse the A panel from L2.
// MODE 0: +bias, relu, bf16 store (ldc stride)
// MODE 1: +bias, bf16 store (EMB stride, col<300) + fused column stats
template <int MODE>
__global__ __launch_bounds__(256) void k_gemm(
    const u16* __restrict__ A, const u16* __restrict__ Bt,
    const float* __restrict__ bias, int nbias,
    u16* __restrict__ Cv, int ldc, int K,
    float* __restrict__ ssum, float* __restrict__ ssq) {
    __shared__ __align__(16) u16 Al[128 * 32];
    __shared__ __align__(16) u16 Bl[128 * 32];
    __shared__ float rs[2][128];
    __shared__ float rq[2][128];
    int t = threadIdx.x;
    int flat = xcd_chunk(blockIdx.y * gridDim.x + blockIdx.x,
                         gridDim.x * gridDim.y);
    int n0 = (flat % gridDim.x) * 128, m0 = (flat / gridDim.x) * 128;
    int lane = t & 63, w = t >> 6;
    int wr = w >> 1, wc = w & 1;
    int lr = lane >> 2, lc = lane & 3;
    const u16* gA0 = A + (size_t)(m0 + w * 32 + lr) * K + lc * 8;
    const u16* gA1 = gA0 + (size_t)16 * K;
    const u16* gB0 = Bt + (size_t)(n0 + w * 32 + lr) * K + lc * 8;
    const u16* gB1 = gB0 + (size_t)16 * K;
    u16* lA0 = &Al[(w * 32) * 32];
    u16* lA1 = &Al[(w * 32 + 16) * 32];
    u16* lB0 = &Bl[(w * 32) * 32];
    u16* lB1 = &Bl[(w * 32 + 16) * 32];
    f32x4 acc[4][4];
#pragma unroll
    for (int i = 0; i < 4; i++)
#pragma unroll
        for (int j = 0; j < 4; j++) acc[i][j] = (f32x4){0.f, 0.f, 0.f, 0.f};
    int fr = lane & 15;
    int k0 = (lane >> 4) * 8;
    int abase = (wr * 64 + fr) * 32 + k0;
    int bbase = (wc * 64 + fr) * 32 + k0;
    for (int kt = 0; kt < K; kt += 32) {
        if (kt) __syncthreads();
        gload_lds16(gA0 + kt, lA0);
        gload_lds16(gA1 + kt, lA1);
        gload_lds16(gB0 + kt, lB0);
        gload_lds16(gB1 + kt, lB1);
        __syncthreads();
        bf16x8 af[4], bfv[4];
#pragma unroll
        for (int f = 0; f < 4; ++f) {
            af[f]  = *reinterpret_cast<const bf16x8*>(&Al[abase + f * 16 * 32]);
            bfv[f] = *reinterpret_cast<const bf16x8*>(&Bl[bbase + f * 16 * 32]);
        }
#pragma unroll
        for (int fm = 0; fm < 4; ++fm)
#pragma unroll
            for (int fn = 0; fn < 4; ++fn)
                acc[fm][fn] = __builtin_amdgcn_mfma_f32_16x16x32_bf16(
                    af[fm], bfv[fn], acc[fm][fn], 0, 0, 0);
    }
    int rg = lane >> 4;
    if (MODE == 0) {
#pragma unroll
        for (int fn = 0; fn < 4; ++fn) {
            int col = n0 + wc * 64 + fn * 16 + fr;
            float bv = (col < nbias) ? bias[col] : 0.f;
#pragma unroll
            for (int fm = 0; fm < 4; ++fm) {
                int rb = m0 + wr * 64 + fm * 16 + rg * 4;
#pragma unroll
                for (int j = 0; j < 4; ++j) {
                    float v = fmaxf(acc[fm][fn][j] + bv, 0.f);
                    Cv[(size_t)(rb + j) * ldc + col] = f2bf(v);
                }
            }
        }
    } else {
#pragma unroll
        for (int fn = 0; fn < 4; ++fn) {
            int col = n0 + wc * 64 + fn * 16 + fr;
            float bv = (col < nbias) ? bias[col] : 0.f;
            float cs = 0.f, cq = 0.f;
#pragma unroll
            for (int fm = 0; fm < 4; ++fm) {
                int rb = m0 + wr * 64 + fm * 16 + rg * 4;
#pragma unroll
                for (int j = 0; j < 4; ++j) {
                    float v = acc[fm][fn][j] + bv;
                    if (col < EMB) Cv[(size_t)(rb + j) * EMB + col] = f2bf(v);
                    cs += v;
                    cq += v * v;
                }
            }
            cs += __shfl_xor(cs, 16); cs += __shfl_xor(cs, 32);
            cq += __shfl_xor(cq, 16); cq += __shfl_xor(cq, 32);
            if (rg == 0) {
                rs[wr][wc * 64 + fn * 16 + fr] = cs;
                rq[wr][wc * 64 + fn * 16 + fr] = cq;
            }
        }
        __syncthreads();
        if (t < 128) {
            int col = n0 + t;
            if (col < EMB) {
                atomicAdd(&ssum[col], rs[0][t] + rs[1][t]);
                atomicAdd(&ssq[col], rq[0][t] + rq[1][t]);
            }
        }
    }
}

// ---------------- tail: pool (fused final BN), head GEMMs ----------------------
__global__ __launch_bounds__(256) void k_pool(const u16* __restrict__ h,
                                              const int* __restrict__ goff,
                                              const float* __restrict__ ssum,
                                              const float* __restrict__ ssq,
                                              const float* __restrict__ bng,
                                              const float* __restrict__ bnb,
                                              float* __restrict__ hg) {
    __shared__ float red[4][64];
    int g = blockIdx.x;
    int col = blockIdx.y * 64 + (threadIdx.x & 63);
    int w = threadIdx.x >> 6;
    int s = goff[g], e = goff[g + 1];
    float a = 0.f;
    bool ok = col < EMB;
    if (ok) {
        for (int r = s + w; r < e; r += 4)
            a += __builtin_bit_cast(float, (u32)h[(size_t)r * EMB + col] << 16);
    }
    red[w][threadIdx.x & 63] = a;
    __syncthreads();
    if (w == 0 && ok) {
        float sc, tc;
        bn_coef_v(ssum[col], ssq[col], bng[col], bnb[col], sc, tc);
        float v = red[0][threadIdx.x] + red[1][threadIdx.x] +
                  red[2][threadIdx.x] + red[3][threadIdx.x];
        float inv = (e > s) ? 1.0f / (float)(e - s) : 0.f;
        hg[(size_t)g * EMB + col] = (v * inv) * sc + tc;
    }
}

template <int ACT>  // 0: none, 1: softplus
__global__ __launch_bounds__(256) void k_small_mm(
    const float* __restrict__ A, const float* __restrict__ W,
    const float* __restrict__ bias, float* __restrict__ C, int N, int K) {
    __shared__ float red[4][64];
    int row = blockIdx.x;
    int lane = threadIdx.x & 63;
    int col = blockIdx.y * 64 + lane;
    int w = threadIdx.x >> 6;
    const float* a = A + (size_t)row * K;
    float acc = 0.f;
#pragma unroll 4
    for (int k = w; k < K; k += 4) acc += a[k] * W[(size_t)k * N + col];
    red[w][lane] = acc;
    __syncthreads();
    if (w == 0) {
        float v = red[0][lane] + red[1][lane] + red[2][lane] + red[3][lane] + bias[col];
        if (ACT) v = softplus_f(v);
        C[(size_t)row * N + col] = v;
    }
}

__global__ __launch_bounds__(256) void k_pred(const float* __restrict__ P,
                                              const float* __restrict__ hw3,
                                              const float* __restrict__ hb3,
                                              float* __restrict__ out) {
    __shared__ float red[2][4];
    int g = blockIdx.x;
    int t = threadIdx.x;
    float q = P[(size_t)g * 256 + t];
    float r0 = q * hw3[t * 2 + 0];
    float r1 = q * hw3[t * 2 + 1];
#pragma unroll
    for (int off = 32; off > 0; off >>= 1) {
        r0 += __shfl_down(r0, off);
        r1 += __shfl_down(r1, off);
    }
    if ((t & 63) == 0) { red[0][t >> 6] = r0; red[1][t >> 6] = r1; }
    __syncthreads();
    if (t == 0) {
        out[(size_t)NGRAPH * 512 + g * 2 + 0] = red[0][0] + red[0][1] + red[0][2] + red[0][3] + hb3[0];
        out[(size_t)NGRAPH * 512 + g * 2 + 1] = red[1][0] + red[1][1] + red[1][2] + red[1][3] + hb3[1];
    }
}

// ---------------- launch ----------------
extern "C" void kernel_launch(void* const* d_in, const int* in_sizes, int n_in,
                              void* d_out, int out_size, void* d_ws, size_t ws_size,
                              hipStream_t stream) {
    const int* x      = (const int*)d_in[0];
    const int* ei     = (const int*)d_in[1];
    const int* ea     = (const int*)d_in[2];
    const int* batch  = (const int*)d_in[3];
    const float* x_emb1 = (const float*)d_in[4];
    const float* x_emb2 = (const float*)d_in[5];
    const float* e1_emb = (const float*)d_in[6];
    const float* e2_emb = (const float*)d_in[7];
    const float* w1   = (const float*)d_in[8];
    const float* b1   = (const float*)d_in[9];
    const float* w2   = (const float*)d_in[10];
    const float* b2   = (const float*)d_in[11];
    const float* bn_g = (const float*)d_in[12];
    const float* bn_b = (const float*)d_in[13];
    const float* feat_w = (const float*)d_in[14];
    const float* feat_b = (const float*)d_in[15];
    const float* hw1  = (const float*)d_in[16];
    const float* hb1  = (const float*)d_in[17];
    const float* hw2  = (const float*)d_in[18];
    const float* hb2  = (const float*)d_in[19];
    const float* hw3  = (const float*)d_in[20];
    const float* hb3  = (const float*)d_in[21];
    float* out = (float*)d_out;

    char* p = (char*)d_ws;
    auto alloc = [&](size_t bytes) -> char* {
        char* r = p;
        p += ((bytes + 255) / 256) * 256;
        return r;
    };
    u16* h_a     = (u16*)alloc((size_t)NODES * EMB * 2);   // current h (pre-BN)
    u16* h_b     = (u16*)alloc((size_t)NODES * EMB * 2);   // post-BN h'
    u16* aggB    = (u16*)alloc((size_t)NODES * KP1 * 2);
    u16* T       = (u16*)alloc((size_t)NODES * NP1 * 2);
    u16* w1bT    = (u16*)alloc((size_t)LAYERS * NP1 * KP1 * 2);
    u16* w2bT    = (u16*)alloc((size_t)LAYERS * NP2B * NP1 * 2);
    u16* comb    = (u16*)alloc((size_t)LAYERS * 18 * EMB * 2);
    int* row_off = (int*)alloc((NODES + 1) * 4);
    int* packed  = (int*)alloc((size_t)EDGES * 4);
    int* goff    = (int*)alloc((NGRAPH + 1) * 4);
    float* hg    = (float*)alloc((size_t)NGRAPH * EMB * 4);
    float* pb1   = (float*)alloc((size_t)NGRAPH * 256 * 4);
    float* pb2   = (float*)alloc((size_t)NGRAPH * 256 * 4);
    // cursor + per-layer stats contiguous -> single memset
    int* cursor  = (int*)alloc(NODES * 4);                 // 64000 B (256-mult)
    float* stats5 = (float*)alloc((size_t)LAYERS * 640 * 4);  // [l][ssum320|ssq320]
    if ((size_t)(p - (char*)d_ws) > ws_size) return;  // workspace too small

    hipMemsetAsync(cursor, 0, NODES * 4 + LAYERS * 640 * 4, stream);

    // CSR build (real edges only; self-loops analytic in k_aggregate)
    k_count<<<(EDGES + 255) / 256, 256, 0, stream>>>(ei, cursor);
    k_scan<<<1, 1024, 0, stream>>>(cursor, row_off, cursor);
    k_fill<<<(EDGES + 255) / 256, 256, 0, stream>>>(ei, ea, cursor, packed);

    // fused setup: embed -> h_a, comb, w1bT, w2bT, goff
    k_setup<<<(SETUP_TOT + 255) / 256, 256, 0, stream>>>(
        x, x_emb1, x_emb2, e1_emb, e2_emb, w1, w2, batch,
        h_a, comb, w1bT, w2bT, goff);

    for (int l = 0; l < LAYERS; ++l) {
        const u16* h_src;
        if (l == 0) {
            h_src = h_a;
        } else {
            float* st = stats5 + (size_t)(l - 1) * 640;
            k_bnrelu<<<(NODES * EMB / 4 + 255) / 256, 256, 0, stream>>>(
                h_a, h_b, st, st + 320, bn_g + (l - 1) * EMB, bn_b + (l - 1) * EMB);
            h_src = h_b;
        }
        k_aggregate<<<NODES / 4, 256, 0, stream>>>(
            h_src, row_off, packed, comb + (size_t)l * 18 * EMB, aggB);
        k_gemm<0><<<dim3(NP1 / 128, NODES / 128), 256, 0, stream>>>(
            aggB, w1bT + (size_t)l * NP1 * KP1, b1 + l * 600, 600, T, NP1, KP1,
            nullptr, nullptr);
        float* st = stats5 + (size_t)l * 640;
        k_gemm<1><<<dim3(NP2B / 128, NODES / 128), 256, 0, stream>>>(
            T, w2bT + (size_t)l * NP2B * NP1, b2 + l * EMB, EMB, h_a, 0, NP1,
            st, st + 320);
    }

    // h_a holds layer-4 pre-BN output; pool applies BN affine post-mean
    float* st4 = stats5 + (size_t)4 * 640;
    k_pool<<<dim3(NGRAPH, 5), 256, 0, stream>>>(h_a, goff, st4, st4 + 320,
                                                bn_g + 4 * EMB, bn_b + 4 * EMB, hg);
    k_small_mm<0><<<dim3(NGRAPH, 8), 256, 0, stream>>>(hg, feat_w, feat_b, out, 512, EMB);
    k_small_mm<1><<<dim3(NGRAPH, 4), 256, 0, stream>>>(out, hw1, hb1, pb1, 256, 512);
    k_small_mm<1><<<dim3(NGRAPH, 4), 256, 0, stream>>>(pb1, hw2, hb2, pb2, 256, 256);
    k_pred<<<NGRAPH, 256, 0, stream>>>(pb2, hw3, hb3, out);
}